// Round 16
// baseline (90.376 us; speedup 1.0000x reference)
//
#include <hip/hip_runtime.h>
#include <hip/hip_bf16.h>
#include <stdint.h>

// DotReluAttention: out = relu(Q K^T / 64) V   (B=2,H=8,S=4096,D=64, fp32 io)
// Pre-pass: fp32->bf16 ws in MFMA-FRAGMENT ORDER (1KB chunks, lane l <- chunk + l*16).
// Main (R16 = T15 double-P pipeline): 512-thr blocks = 2 k-groups x 4 q-waves (m=1,
//   32 rows/wave). Per half-iter: QK^T(kt) -> loadK(kt+1) -> [PV(kt-1) INTERLEAVED
//   with pack(kt)] -> loadV(kt). Two P states (paA/paB) break the MFMA->VALU->MFMA
//   serialization: PV rides the matrix pipe while pack rides VALU. Barrier-free,
//   all-register, rotated loads, cvt_pk + permlane32_swap + packed-f16 relu,
//   XCD-chunked swizzle.

#define NH 16
#define SEQ 4096
#define DD 64
#define HE (SEQ*DD)            // 262144 elems / head
#define HB (HE*2)              // 524288 bytes / head (bf16)
#define Q16_OFF 0
#define K16_OFF (NH*HB)        // 8388608
#define V16_OFF (2*NH*HB)      // 16777216
#define WS_NEED (3*NH*HB)      // 25165824

typedef __attribute__((ext_vector_type(8)))  short    bf16x8;
typedef __attribute__((ext_vector_type(16))) float    f32x16;
typedef __attribute__((ext_vector_type(4)))  uint32_t u32x4;

__device__ inline uint32_t f2bf1(float f) {
  return (uint32_t)__builtin_bit_cast(unsigned short, __float2bfloat16(f));
}
__device__ inline uint32_t pack2bf(float a, float b) {
  return f2bf1(a) | (f2bf1(b) << 16);
}
// one-op pack: dst = {bf16(lo), bf16(hi)} (RNE)
__device__ inline uint32_t cvtpk(float lo, float hi) {
  uint32_t r;
  asm("v_cvt_pk_bf16_f32 %0, %1, %2" : "=v"(r) : "v"(lo), "v"(hi));
  return r;
}
// relu on a packed pair of bf16 via v_pk_max_f16 (bit-pattern order-isomorphism
// for finite values, sign in bit15): max(x, +0) zeroes exactly the negatives.
__device__ inline uint32_t relu2(uint32_t w) {
  uint32_t r;
  asm("v_pk_max_f16 %0, %1, 0" : "=v"(r) : "v"(w));
  return r;
}

__global__ __launch_bounds__(256) void prepass_kernel(const float* __restrict__ Q,
                                                      const float* __restrict__ K,
                                                      const float* __restrict__ V,
                                                      char* __restrict__ ws) {
  __shared__ float vt[64*65];
  int bx = blockIdx.x, tid = threadIdx.x;
  if (bx < 2048) {                       // Q: scale 1/64, fragment order per 32-row group
    int head = bx >> 7, qg = bx & 127;
    int r31 = tid & 31, c = tid >> 5;    // c in 0..7: t = c>>1, h = c&1
    const float4* s = (const float4*)(Q + (size_t)head*HE + ((size_t)(qg*32 + r31))*64 + c*8);
    float4 a = s[0], b = s[1];
    const float sc = 1.0f/64.0f;
    u32x4 o;
    o.x = pack2bf(a.x*sc, a.y*sc);
    o.y = pack2bf(a.z*sc, a.w*sc);
    o.z = pack2bf(b.x*sc, b.y*sc);
    o.w = pack2bf(b.z*sc, b.w*sc);
    char* tb = ws + Q16_OFF + (size_t)head*HB;
    *(u32x4*)(tb + ((qg*4 + (c >> 1))*1024) + ((c & 1)*32 + r31)*16) = o;
  } else if (bx < 3072) {                // K: 64x64 tiles, fragment order (n,t chunks)
    int tile = bx - 2048;
    int head = tile >> 6, t = tile & 63;
    int r = tid >> 2, c0 = (tid & 3) * 16;
    const float4* s4 = (const float4*)(K + (size_t)head*HE + ((size_t)(t*64 + r))*64 + c0);
    float4 f0 = s4[0], f1 = s4[1], f2 = s4[2], f3 = s4[3];
    u32x4 c_lo, c_hi;
    c_lo.x = pack2bf(f0.x, f0.y); c_lo.y = pack2bf(f0.z, f0.w);
    c_lo.z = pack2bf(f1.x, f1.y); c_lo.w = pack2bf(f1.z, f1.w);
    c_hi.x = pack2bf(f2.x, f2.y); c_hi.y = pack2bf(f2.z, f2.w);
    c_hi.z = pack2bf(f3.x, f3.y); c_hi.w = pack2bf(f3.z, f3.w);
    char* tb = ws + K16_OFF + ((size_t)head*64 + t)*8192;
    char* chunk = tb + ((r >> 5)*4 + (tid & 3))*1024 + (r & 31)*16;
    *(u32x4*)(chunk)       = c_lo;   // h=0 half (elems t*16..+8)
    *(u32x4*)(chunk + 512) = c_hi;   // h=1 half
  } else {                               // V: transpose via LDS -> V^T tiles, fragment order (nd,ks)
    int tile = bx - 3072;
    int head = tile >> 6, t = tile & 63;
    int k = tid >> 2, c0 = (tid & 3)*16;
    const float4* s4 = (const float4*)(V + (size_t)head*HE + ((size_t)(t*64 + k))*64 + c0);
    float4 f0 = s4[0], f1 = s4[1], f2 = s4[2], f3 = s4[3];
    float tmp[16] = {f0.x,f0.y,f0.z,f0.w, f1.x,f1.y,f1.z,f1.w,
                     f2.x,f2.y,f2.z,f2.w, f3.x,f3.y,f3.z,f3.w};
    #pragma unroll
    for (int j = 0; j < 16; ++j) vt[k*65 + c0 + j] = tmp[j];
    __syncthreads();
    int d = tid >> 2, k0 = (tid & 3)*16;
    float v2[16];
    #pragma unroll
    for (int j = 0; j < 16; ++j) v2[j] = vt[(k0 + j)*65 + d];
    u32x4 c_lo, c_hi;
    c_lo.x = pack2bf(v2[0],  v2[1]);  c_lo.y = pack2bf(v2[2],  v2[3]);
    c_lo.z = pack2bf(v2[4],  v2[5]);  c_lo.w = pack2bf(v2[6],  v2[7]);
    c_hi.x = pack2bf(v2[8],  v2[9]);  c_hi.y = pack2bf(v2[10], v2[11]);
    c_hi.z = pack2bf(v2[12], v2[13]); c_hi.w = pack2bf(v2[14], v2[15]);
    char* tb = ws + V16_OFF + ((size_t)head*64 + t)*8192;
    char* chunk = tb + ((d >> 5)*4 + (tid & 3))*1024 + (d & 31)*16;
    *(u32x4*)(chunk)       = c_lo;   // h=0 half (k-elems k0..+8)
    *(u32x4*)(chunk + 512) = c_hi;   // h=1 half
  }
}

__global__ __launch_bounds__(512, 2) void attn_kernel(const char* __restrict__ ws,
                                                      float* __restrict__ out) {
  __shared__ float red[128*64];   // 32KB, epilogue only
  // XCD-chunked swizzle: 64 consecutive logical blocks (2 heads) per XCD.
  int bid = blockIdx.x;
  int bx = (bid & 7) * 64 + (bid >> 3);
  int head = bx >> 5, qblk = bx & 31;
  int tid = threadIdx.x;
  int lane = tid & 63, w = tid >> 6;
  int l31 = lane & 31, h = lane >> 5;
  int g  = w >> 2;    // k-group: tiles [g*32, g*32+32)
  int wq = w & 3;     // q-quarter (32 rows, m=1)

  const char* q16   = ws + Q16_OFF + (size_t)head*HB;
  const char* kbase = ws + K16_OFF + (size_t)head*HB + (size_t)g*32*8192;
  const char* vbase = ws + V16_OFF + (size_t)head*HB + (size_t)g*32*8192;

  // Q fragments (m=1)
  int qg = qblk*4 + wq;
  bf16x8 qf[4];
  #pragma unroll
  for (int t = 0; t < 4; ++t)
    qf[t] = *(const bf16x8*)(q16 + ((size_t)(qg*4 + t))*1024 + lane*16);

  f32x16 kZero;
  #pragma unroll
  for (int i = 0; i < 16; ++i) kZero[i] = 0.f;

  f32x16 o[2];
  #pragma unroll
  for (int nd = 0; nd < 2; ++nd)
    #pragma unroll
    for (int i = 0; i < 16; ++i) o[nd][i] = 0.f;

  // single-buffered kf/vf (rotated refill); DOUBLE P state (T15)
  bf16x8 kf[2][4], vf[2][4], paA[4], paB[4];
  f32x16 st[2];

  auto loadK = [&](int kt) {
    const char* kp = kbase + (size_t)kt*8192;
    #pragma unroll
    for (int i = 0; i < 8; ++i)
      kf[i >> 2][i & 3] = *(const bf16x8*)(kp + i*1024 + lane*16);
  };
  auto loadV = [&](int kt) {
    const char* vp = vbase + (size_t)kt*8192;
    #pragma unroll
    for (int i = 0; i < 8; ++i)
      vf[i >> 2][i & 3] = *(const bf16x8*)(vp + i*1024 + lane*16);
  };
  auto qkt = [&]() {          // 8 MFMA, chain-interleaved (n outer-rotated)
    __builtin_amdgcn_s_setprio(1);
    st[0] = __builtin_amdgcn_mfma_f32_32x32x16_bf16(kf[0][0], qf[0], kZero, 0, 0, 0);
    st[1] = __builtin_amdgcn_mfma_f32_32x32x16_bf16(kf[1][0], qf[0], kZero, 0, 0, 0);
    #pragma unroll
    for (int t = 1; t < 4; ++t) {
      st[0] = __builtin_amdgcn_mfma_f32_32x32x16_bf16(kf[0][t], qf[t], st[0], 0, 0, 0);
      st[1] = __builtin_amdgcn_mfma_f32_32x32x16_bf16(kf[1][t], qf[t], st[1], 0, 0, 0);
    }
    __builtin_amdgcn_s_setprio(0);
  };
  // one pack group (n,kn): st -> 4 words of paDst[n*2+kn]
  auto packg = [&](bf16x8* paDst, int n, int kn) {
    uint32_t w0 = cvtpk(st[n][kn*8+0], st[n][kn*8+1]);
    uint32_t w1 = cvtpk(st[n][kn*8+2], st[n][kn*8+3]);
    uint32_t w2 = cvtpk(st[n][kn*8+4], st[n][kn*8+5]);
    uint32_t w3 = cvtpk(st[n][kn*8+6], st[n][kn*8+7]);
    asm("v_permlane32_swap_b32 %0, %1" : "+v"(w0), "+v"(w2));
    asm("v_permlane32_swap_b32 %0, %1" : "+v"(w1), "+v"(w3));
    union { uint32_t u[4]; bf16x8 v; } pk;
    pk.u[0] = relu2(w0);
    pk.u[1] = relu2(w1);
    pk.u[2] = relu2(w2);
    pk.u[3] = relu2(w3);
    paDst[n*2 + kn] = pk.v;
  };
  // PV(prev) INTERLEAVED with pack(cur): paSrc feeds MFMA (matrix pipe) while
  // st packs into paDst (VALU pipe) — no data deps between the two streams.
  auto pv_pack = [&](bf16x8* paSrc, bf16x8* paDst) {
    __builtin_amdgcn_s_setprio(1);
    o[0] = __builtin_amdgcn_mfma_f32_32x32x16_bf16(paSrc[0], vf[0][0], o[0], 0, 0, 0);
    o[1] = __builtin_amdgcn_mfma_f32_32x32x16_bf16(paSrc[0], vf[1][0], o[1], 0, 0, 0);
    packg(paDst, 0, 0);
    o[0] = __builtin_amdgcn_mfma_f32_32x32x16_bf16(paSrc[1], vf[0][1], o[0], 0, 0, 0);
    o[1] = __builtin_amdgcn_mfma_f32_32x32x16_bf16(paSrc[1], vf[1][1], o[1], 0, 0, 0);
    packg(paDst, 0, 1);
    o[0] = __builtin_amdgcn_mfma_f32_32x32x16_bf16(paSrc[2], vf[0][2], o[0], 0, 0, 0);
    o[1] = __builtin_amdgcn_mfma_f32_32x32x16_bf16(paSrc[2], vf[1][2], o[1], 0, 0, 0);
    packg(paDst, 1, 0);
    o[0] = __builtin_amdgcn_mfma_f32_32x32x16_bf16(paSrc[3], vf[0][3], o[0], 0, 0, 0);
    o[1] = __builtin_amdgcn_mfma_f32_32x32x16_bf16(paSrc[3], vf[1][3], o[1], 0, 0, 0);
    packg(paDst, 1, 1);
    __builtin_amdgcn_s_setprio(0);
  };

  // prologue: K(0)->kf, V(0)->vf; QKT(0); K(1)->kf; pack->paA
  loadK(0);
  loadV(0);
  qkt();                 // tile 0
  loadK(1);
  packg(paA, 0, 0); packg(paA, 0, 1); packg(paA, 1, 0); packg(paA, 1, 1);

  #pragma unroll 1
  for (int kt = 1; kt < 31; kt += 2) {
    // half-iter kt (odd): PV(kt-1) from paA, pack(kt) -> paB
    qkt();                         // QKT(kt), kf=K(kt)
    loadK(kt + 1);
    pv_pack(paA, paB);             // PV uses vf=V(kt-1)
    loadV(kt);                     // vf <- V(kt) (dead after PV)
    // half-iter kt+1 (even): PV(kt) from paB, pack(kt+1) -> paA
    qkt();                         // QKT(kt+1), kf=K(kt+1)
    loadK(kt + 2);                 // max kt+2 = 31
    pv_pack(paB, paA);             // PV uses vf=V(kt)
    loadV(kt + 1);                 // vf <- V(kt+1)
  }
  // tail: QKT(31) done? loop covered QKT 1..30; kf=K(31), paA=P(30), vf=V(30)
  qkt();                           // QKT(31)
  pv_pack(paA, paB);               // PV(30), pack P(31)->paB
  loadV(31);
  __builtin_amdgcn_s_setprio(1);
  #pragma unroll
  for (int ks = 0; ks < 4; ++ks) {
    o[0] = __builtin_amdgcn_mfma_f32_32x32x16_bf16(paB[ks], vf[0][ks], o[0], 0, 0, 0);
    o[1] = __builtin_amdgcn_mfma_f32_32x32x16_bf16(paB[ks], vf[1][ks], o[1], 0, 0, 0);
  }
  __builtin_amdgcn_s_setprio(0);

  // cross-k-group O reduction: g1 -> LDS, g0 adds and stores
  __syncthreads();
  if (g == 1) {
    #pragma unroll
    for (int nd = 0; nd < 2; ++nd)
      #pragma unroll
      for (int r = 0; r < 16; ++r) {
        int ql = wq*32 + (r & 3) + 8*(r >> 2) + 4*h;
        red[ql*64 + nd*32 + l31] = o[nd][r];
      }
  }
  __syncthreads();
  if (g == 0) {
    float* outh = out + (size_t)head*HE;
    #pragma unroll
    for (int nd = 0; nd < 2; ++nd)
      #pragma unroll
      for (int r = 0; r < 16; ++r) {
        int ql = wq*32 + (r & 3) + 8*(r >> 2) + 4*h;
        float v = o[nd][r] + red[ql*64 + nd*32 + l31];
        outh[(size_t)(qblk*128 + ql)*64 + nd*32 + l31] = v;
      }
  }
}

extern "C" void kernel_launch(void* const* d_in, const int* in_sizes, int n_in,
                              void* d_out, int out_size, void* d_ws, size_t ws_size,
                              hipStream_t stream) {
  if (n_in < 3 || ws_size < (size_t)WS_NEED) return;  // ws too small -> fail visibly
  const float* Q = (const float*)d_in[0];
  const float* K = (const float*)d_in[1];
  const float* V = (const float*)d_in[2];
  float* out = (float*)d_out;
  char* ws = (char*)d_ws;
  hipLaunchKernelGGL(prepass_kernel, dim3(4096), dim3(256), 0, stream, Q, K, V, ws);
  hipLaunchKernelGGL(attn_kernel,    dim3(512),  dim3(512), 0, stream, ws, out);
}

// Round 17
// 78.936 us; speedup vs baseline: 1.1449x; 1.1449x over previous
//
#include <hip/hip_runtime.h>
#include <hip/hip_bf16.h>
#include <stdint.h>

// DotReluAttention: out = relu(Q K^T / 64) V   (B=2,H=8,S=4096,D=64, fp32 io)
// Pre-pass: fp32->bf16 ws in MFMA-FRAGMENT ORDER (1KB chunks, lane l <- chunk + l*16).
// Main (R17): K AND V staged via global_load_lds (fragment-order linear copy),
//   double-buffered, ONE barrier/iter (vmcnt(0) -> s_barrier -> stage(kt+1): any
//   stager passed barrier(kt) => all waves finished compute(kt-1), the buffer's
//   last readers). L1-port traffic /4 vs register loads. ds_read_b128 fragments,
//   intra-tile pack||PV interleave (pack n=1 under PV ks=0,1 shadow).
//   256-thr = 2 k-groups x 2 q-halves (m=2), 32x32x16 MFMA, swapped QK^T,
//   cvt_pk + permlane32_swap + packed-f16 relu, setprio, XCD-chunked swizzle.

#define NH 16
#define SEQ 4096
#define DD 64
#define HE (SEQ*DD)            // 262144 elems / head
#define HB (HE*2)              // 524288 bytes / head (bf16)
#define Q16_OFF 0
#define K16_OFF (NH*HB)        // 8388608
#define V16_OFF (2*NH*HB)      // 16777216
#define WS_NEED (3*NH*HB)      // 25165824

typedef __attribute__((ext_vector_type(8)))  short    bf16x8;
typedef __attribute__((ext_vector_type(16))) float    f32x16;
typedef __attribute__((ext_vector_type(4)))  uint32_t u32x4;

__device__ inline uint32_t f2bf1(float f) {
  return (uint32_t)__builtin_bit_cast(unsigned short, __float2bfloat16(f));
}
__device__ inline uint32_t pack2bf(float a, float b) {
  return f2bf1(a) | (f2bf1(b) << 16);
}
// one-op pack: dst = {bf16(lo), bf16(hi)} (RNE)
__device__ inline uint32_t cvtpk(float lo, float hi) {
  uint32_t r;
  asm("v_cvt_pk_bf16_f32 %0, %1, %2" : "=v"(r) : "v"(lo), "v"(hi));
  return r;
}
// relu on a packed pair of bf16 via v_pk_max_f16 (bit-pattern order-isomorphism
// for finite values, sign in bit15): max(x, +0) zeroes exactly the negatives.
__device__ inline uint32_t relu2(uint32_t w) {
  uint32_t r;
  asm("v_pk_max_f16 %0, %1, 0" : "=v"(r) : "v"(w));
  return r;
}

__global__ __launch_bounds__(256) void prepass_kernel(const float* __restrict__ Q,
                                                      const float* __restrict__ K,
                                                      const float* __restrict__ V,
                                                      char* __restrict__ ws) {
  __shared__ float vt[64*65];
  int bx = blockIdx.x, tid = threadIdx.x;
  if (bx < 2048) {                       // Q: scale 1/64, fragment order per 32-row group
    int head = bx >> 7, qg = bx & 127;
    int r31 = tid & 31, c = tid >> 5;    // c in 0..7: t = c>>1, h = c&1
    const float4* s = (const float4*)(Q + (size_t)head*HE + ((size_t)(qg*32 + r31))*64 + c*8);
    float4 a = s[0], b = s[1];
    const float sc = 1.0f/64.0f;
    u32x4 o;
    o.x = pack2bf(a.x*sc, a.y*sc);
    o.y = pack2bf(a.z*sc, a.w*sc);
    o.z = pack2bf(b.x*sc, b.y*sc);
    o.w = pack2bf(b.z*sc, b.w*sc);
    char* tb = ws + Q16_OFF + (size_t)head*HB;
    *(u32x4*)(tb + ((qg*4 + (c >> 1))*1024) + ((c & 1)*32 + r31)*16) = o;
  } else if (bx < 3072) {                // K: 64x64 tiles, fragment order (n,t chunks)
    int tile = bx - 2048;
    int head = tile >> 6, t = tile & 63;
    int r = tid >> 2, c0 = (tid & 3) * 16;
    const float4* s4 = (const float4*)(K + (size_t)head*HE + ((size_t)(t*64 + r))*64 + c0);
    float4 f0 = s4[0], f1 = s4[1], f2 = s4[2], f3 = s4[3];
    u32x4 c_lo, c_hi;
    c_lo.x = pack2bf(f0.x, f0.y); c_lo.y = pack2bf(f0.z, f0.w);
    c_lo.z = pack2bf(f1.x, f1.y); c_lo.w = pack2bf(f1.z, f1.w);
    c_hi.x = pack2bf(f2.x, f2.y); c_hi.y = pack2bf(f2.z, f2.w);
    c_hi.z = pack2bf(f3.x, f3.y); c_hi.w = pack2bf(f3.z, f3.w);
    char* tb = ws + K16_OFF + ((size_t)head*64 + t)*8192;
    char* chunk = tb + ((r >> 5)*4 + (tid & 3))*1024 + (r & 31)*16;
    *(u32x4*)(chunk)       = c_lo;   // h=0 half (elems t*16..+8)
    *(u32x4*)(chunk + 512) = c_hi;   // h=1 half
  } else {                               // V: transpose via LDS -> V^T tiles, fragment order (nd,ks)
    int tile = bx - 3072;
    int head = tile >> 6, t = tile & 63;
    int k = tid >> 2, c0 = (tid & 3)*16;
    const float4* s4 = (const float4*)(V + (size_t)head*HE + ((size_t)(t*64 + k))*64 + c0);
    float4 f0 = s4[0], f1 = s4[1], f2 = s4[2], f3 = s4[3];
    float tmp[16] = {f0.x,f0.y,f0.z,f0.w, f1.x,f1.y,f1.z,f1.w,
                     f2.x,f2.y,f2.z,f2.w, f3.x,f3.y,f3.z,f3.w};
    #pragma unroll
    for (int j = 0; j < 16; ++j) vt[k*65 + c0 + j] = tmp[j];
    __syncthreads();
    int d = tid >> 2, k0 = (tid & 3)*16;
    float v2[16];
    #pragma unroll
    for (int j = 0; j < 16; ++j) v2[j] = vt[(k0 + j)*65 + d];
    u32x4 c_lo, c_hi;
    c_lo.x = pack2bf(v2[0],  v2[1]);  c_lo.y = pack2bf(v2[2],  v2[3]);
    c_lo.z = pack2bf(v2[4],  v2[5]);  c_lo.w = pack2bf(v2[6],  v2[7]);
    c_hi.x = pack2bf(v2[8],  v2[9]);  c_hi.y = pack2bf(v2[10], v2[11]);
    c_hi.z = pack2bf(v2[12], v2[13]); c_hi.w = pack2bf(v2[14], v2[15]);
    char* tb = ws + V16_OFF + ((size_t)head*64 + t)*8192;
    char* chunk = tb + ((d >> 5)*4 + (tid & 3))*1024 + (d & 31)*16;
    *(u32x4*)(chunk)       = c_lo;   // h=0 half (k-elems k0..+8)
    *(u32x4*)(chunk + 512) = c_hi;   // h=1 half
  }
}

__global__ __launch_bounds__(256, 2) void attn_kernel(const char* __restrict__ ws,
                                                      float* __restrict__ out) {
  // [grp][buf] x (K 8KB | V 8KB) = 64KB; epilogue red (32KB) overlays.
  __shared__ __align__(16) char lds[2*2*16384];
  // XCD-chunked swizzle: 64 consecutive logical blocks (2 heads) per XCD.
  int bid = blockIdx.x;
  int bx = (bid & 7) * 64 + (bid >> 3);
  int head = bx >> 5, qblk = bx & 31;
  int tid = threadIdx.x;
  int lane = tid & 63, w = tid >> 6;
  int l31 = lane & 31, h = lane >> 5;
  int g  = w >> 1;    // k-group: tiles [g*32, g*32+32)
  int wg = w & 1;     // q-half (64 rows, m=2)

  const char* q16   = ws + Q16_OFF + (size_t)head*HB;
  const char* kbase = ws + K16_OFF + (size_t)head*HB + (size_t)g*32*8192;
  const char* vbase = ws + V16_OFF + (size_t)head*HB + (size_t)g*32*8192;

  // Q fragments, coalesced from fragment-ordered ws
  int qg0 = qblk*4 + wg*2;
  bf16x8 qf[2][4];
  #pragma unroll
  for (int m = 0; m < 2; ++m)
    #pragma unroll
    for (int t = 0; t < 4; ++t)
      qf[m][t] = *(const bf16x8*)(q16 + ((size_t)((qg0 + m)*4 + t))*1024 + lane*16);

  f32x16 kZero;
  #pragma unroll
  for (int i = 0; i < 16; ++i) kZero[i] = 0.f;

  f32x16 o[2][2];
  #pragma unroll
  for (int m = 0; m < 2; ++m)
    #pragma unroll
    for (int nd = 0; nd < 2; ++nd)
      #pragma unroll
      for (int i = 0; i < 16; ++i) o[m][nd][i] = 0.f;

  // stage K+V tile kt into buf (kt&1): group's 16KB split by its 2 waves
  // (each wave: 4 K-chunks + 4 V-chunks of 1KB, linear fragment-order copy).
  auto stage = [&](int kt) {
    const char* ktile = kbase + (size_t)kt*8192;
    const char* vtile = vbase + (size_t)kt*8192;
    char* lk = lds + (size_t)(g*2 + (kt & 1))*16384;
    char* lv = lk + 8192;
    #pragma unroll
    for (int c = 0; c < 4; ++c) {
      int off = (wg*4 + c)*1024;
      __builtin_amdgcn_global_load_lds(
          (const __attribute__((address_space(1))) void*)(ktile + off + lane*16),
          (__attribute__((address_space(3))) void*)(lk + off), 16, 0, 0);
      __builtin_amdgcn_global_load_lds(
          (const __attribute__((address_space(1))) void*)(vtile + off + lane*16),
          (__attribute__((address_space(3))) void*)(lv + off), 16, 0, 0);
    }
  };

  stage(0);
  #pragma unroll 1
  for (int kt = 0; kt < 32; ++kt) {
    // stage(kt) is the only outstanding DMA -> full drain == counted wait.
    asm volatile("s_waitcnt vmcnt(0)" ::: "memory");
    __builtin_amdgcn_s_barrier();         // K/V(kt) resident for all waves
    // prefetch next tile; safe: all waves passed barrier(kt) => finished
    // compute(kt-1), the last readers of buf ((kt+1)&1). Cover = compute(kt).
    if (kt + 1 < 32) stage(kt + 1);

    const char* lk = lds + (size_t)(g*2 + (kt & 1))*16384;
    const char* lv = lk + 8192;

    // K fragments (conflict-free linear b128)
    bf16x8 kf[2][4];
    #pragma unroll
    for (int i = 0; i < 8; ++i)
      kf[i >> 2][i & 3] = *(const bf16x8*)(lk + i*1024 + lane*16);

    // swapped QK^T, chain-interleaved (4 chains m x n)
    f32x16 st[2][2];
    __builtin_amdgcn_s_setprio(1);
    #pragma unroll
    for (int n = 0; n < 2; ++n)
      #pragma unroll
      for (int m = 0; m < 2; ++m)
        st[m][n] = __builtin_amdgcn_mfma_f32_32x32x16_bf16(kf[n][0], qf[m][0], kZero, 0, 0, 0);
    #pragma unroll
    for (int t = 1; t < 4; ++t)
      #pragma unroll
      for (int n = 0; n < 2; ++n)
        #pragma unroll
        for (int m = 0; m < 2; ++m)
          st[m][n] = __builtin_amdgcn_mfma_f32_32x32x16_bf16(kf[n][t], qf[m][t], st[m][n], 0, 0, 0);
    __builtin_amdgcn_s_setprio(0);

    // V fragments (issued here; lgkm waits folded under pack by compiler)
    bf16x8 vf[2][4];
    #pragma unroll
    for (int i = 0; i < 8; ++i)
      vf[i >> 2][i & 3] = *(const bf16x8*)(lv + i*1024 + lane*16);

    // pack helper: group (n,kn) of st -> pa[m][n*2+kn]
    bf16x8 pa[2][4];
    auto packg = [&](int n, int kn) {
      #pragma unroll
      for (int m = 0; m < 2; ++m) {
        uint32_t w0 = cvtpk(st[m][n][kn*8+0], st[m][n][kn*8+1]);
        uint32_t w1 = cvtpk(st[m][n][kn*8+2], st[m][n][kn*8+3]);
        uint32_t w2 = cvtpk(st[m][n][kn*8+4], st[m][n][kn*8+5]);
        uint32_t w3 = cvtpk(st[m][n][kn*8+6], st[m][n][kn*8+7]);
        asm("v_permlane32_swap_b32 %0, %1" : "+v"(w0), "+v"(w2));
        asm("v_permlane32_swap_b32 %0, %1" : "+v"(w1), "+v"(w3));
        union { uint32_t u[4]; bf16x8 v; } pk;
        pk.u[0] = relu2(w0);
        pk.u[1] = relu2(w1);
        pk.u[2] = relu2(w2);
        pk.u[3] = relu2(w3);
        pa[m][n*2 + kn] = pk.v;
      }
    };
    auto pvks = [&](int ks) {
      #pragma unroll
      for (int m = 0; m < 2; ++m)
        #pragma unroll
        for (int nd = 0; nd < 2; ++nd)
          o[m][nd] = __builtin_amdgcn_mfma_f32_32x32x16_bf16(pa[m][ks], vf[nd][ks], o[m][nd], 0, 0, 0);
    };

    // intra-tile interleave: pack n=0 -> PV ks=0 || pack(1,0) -> PV ks=1 ||
    // pack(1,1) -> PV ks=2,3. VALU rides in PV's matrix-pipe shadow.
    packg(0, 0);
    packg(0, 1);
    __builtin_amdgcn_s_setprio(1);
    pvks(0);
    __builtin_amdgcn_s_setprio(0);
    packg(1, 0);
    __builtin_amdgcn_s_setprio(1);
    pvks(1);
    __builtin_amdgcn_s_setprio(0);
    packg(1, 1);
    __builtin_amdgcn_s_setprio(1);
    pvks(2);
    pvks(3);
    __builtin_amdgcn_s_setprio(0);
  }

  // cross-k-group O reduction: g1 -> LDS (overlays staging bufs), g0 adds + stores
  __syncthreads();
  float* red = (float*)lds;
  if (g == 1) {
    #pragma unroll
    for (int m = 0; m < 2; ++m)
      #pragma unroll
      for (int nd = 0; nd < 2; ++nd)
        #pragma unroll
        for (int r = 0; r < 16; ++r) {
          int ql = wg*64 + m*32 + (r & 3) + 8*(r >> 2) + 4*h;
          red[ql*64 + nd*32 + l31] = o[m][nd][r];
        }
  }
  __syncthreads();
  if (g == 0) {
    float* outh = out + (size_t)head*HE;
    #pragma unroll
    for (int m = 0; m < 2; ++m)
      #pragma unroll
      for (int nd = 0; nd < 2; ++nd)
        #pragma unroll
        for (int r = 0; r < 16; ++r) {
          int ql = wg*64 + m*32 + (r & 3) + 8*(r >> 2) + 4*h;
          float v = o[m][nd][r] + red[ql*64 + nd*32 + l31];
          outh[(size_t)(qblk*128 + ql)*64 + nd*32 + l31] = v;
        }
  }
}

extern "C" void kernel_launch(void* const* d_in, const int* in_sizes, int n_in,
                              void* d_out, int out_size, void* d_ws, size_t ws_size,
                              hipStream_t stream) {
  if (n_in < 3 || ws_size < (size_t)WS_NEED) return;  // ws too small -> fail visibly
  const float* Q = (const float*)d_in[0];
  const float* K = (const float*)d_in[1];
  const float* V = (const float*)d_in[2];
  float* out = (float*)d_out;
  char* ws = (char*)d_ws;
  hipLaunchKernelGGL(prepass_kernel, dim3(4096), dim3(256), 0, stream, Q, K, V, ws);
  hipLaunchKernelGGL(attn_kernel,    dim3(512),  dim3(256), 0, stream, ws, out);
}